// Round 6
// baseline (266.510 us; speedup 1.0000x reference)
//
#include <hip/hip_runtime.h>
#include <hip/hip_bf16.h>

// Problem constants (fixed by the reference)
#define LATENT 32
#define HID 64
#define NB 256          // batch (graphs)
#define NN 200000       // nodes
#define NE 1500000      // edges
#define TWOH 128        // 2*HID

// Output layout (flat floats in d_out)
#define OUT_NODE_OFF   0
#define OUT_EDGE_OFF   (NN * 4)                   // 800000
#define OUT_ENERGY_OFF (OUT_EDGE_OFF + NE * 3)    // 5300000
#define OUT_STRESS_OFF (OUT_ENERGY_OFF + NB * 2)  // 5300512

// Workspace layout (flat floats in d_ws)
#define WS_ZPROJ 0
#define WS_ZC    (WS_ZPROJ + NB*TWOH)
#define WS_P1    (WS_ZC + NB*HID)
#define WS_P2    (WS_P1 + NB*HID)
#define WS_T4    (WS_P2 + NB*HID)
#define WS_W1T   (WS_T4 + NB*NB*4)      // fp16 [128ch][128k], k-slot swizzled
#define WS_W2T   (WS_W1T + 8192)        // fp16 [64ch][128k],  k-slot swizzled

typedef _Float16 half8 __attribute__((ext_vector_type(8)));
typedef _Float16 half4 __attribute__((ext_vector_type(4)));
typedef float f32x4 __attribute__((ext_vector_type(4)));
typedef int i32x2 __attribute__((ext_vector_type(2)));
typedef int i32x4 __attribute__((ext_vector_type(4)));

#define WTILES 12500            // 16-node wave tiles
#define NODE_BLK 512            // 2 blocks/CU, one generation
#define WGS 4096                // wave-groups = NODE_BLK*8

// ---------------------------------------------------------------------------
// Kernel 1: per-graph precompute (blocks 0..255) + swizzled fp16 weight
// transpose (blocks 256..319). 256 threads.
// ---------------------------------------------------------------------------
__global__ void precompute_kernel(
    const float* __restrict__ z,
    const float* __restrict__ lp_w, const float* __restrict__ lp_b,
    const float* __restrict__ nd1_w,
    const float* __restrict__ ed1_w,
    const float* __restrict__ en1_w, const float* __restrict__ en1_b,
    const float* __restrict__ en2_w, const float* __restrict__ en2_b,
    const float* __restrict__ st1_w, const float* __restrict__ st1_b,
    const float* __restrict__ st2_w, const float* __restrict__ st2_b,
    const float* __restrict__ nep_w,
    float* __restrict__ z_proj, float* __restrict__ zc,
    float* __restrict__ P1, float* __restrict__ P2,
    _Float16* __restrict__ w1s, _Float16* __restrict__ w2s,
    float* __restrict__ out_energy, float* __restrict__ out_stress)
{
    const int t = threadIdx.x;

    if (blockIdx.x >= NB) {
        const int i = (blockIdx.x - NB) * 256 + t;
        if (i < TWOH * TWOH) {
            const int ch = i >> 7, k = i & 127;
            const int dst = ch * TWOH + (((k >> 3) ^ (ch & 7)) << 3) + (k & 7);
            w1s[dst] = (_Float16)nep_w[k * TWOH + ch];
        }
        if (i < HID * TWOH) {
            const int ch = i >> 7, k = i & 127;
            const int dst = ch * TWOH + (((k >> 3) ^ (ch & 7)) << 3) + (k & 7);
            w2s[dst] = (_Float16)nd1_w[k * HID + ch];
        }
        return;
    }

    const int b = blockIdx.x;
    __shared__ float zrow[LATENT];
    __shared__ float zp[TWOH];
    __shared__ float h_en[HID];
    __shared__ float h_st[HID];

    if (t < LATENT) zrow[t] = z[b * LATENT + t];
    __syncthreads();

    if (t < TWOH) {
        float a = lp_b[t];
        #pragma unroll
        for (int k = 0; k < LATENT; ++k)
            a = fmaf(zrow[k], lp_w[k * TWOH + t], a);
        a = fmaxf(a, 0.f);
        zp[t] = a;
        z_proj[b * TWOH + t] = a;
    }
    if (t < HID) {
        float ae = en1_b[t];
        float as = st1_b[t];
        #pragma unroll
        for (int k = 0; k < LATENT; ++k) {
            ae = fmaf(zrow[k], en1_w[k * HID + t], ae);
            as = fmaf(zrow[k], st1_w[k * HID + t], as);
        }
        h_en[t] = fmaxf(ae, 0.f);
        h_st[t] = fmaxf(as, 0.f);
    }
    __syncthreads();

    if (t < HID) {
        float a = 0.f, p1 = 0.f, p2 = 0.f;
        #pragma unroll 8
        for (int k = 0; k < TWOH; ++k) {
            const float zk = zp[k];
            a  = fmaf(zk, nd1_w[k * HID + t], a);
            p1 = fmaf(zk, ed1_w[k * HID + t], p1);
            p2 = fmaf(zk, ed1_w[(TWOH + k) * HID + t], p2);
        }
        zc[b * HID + t] = a;
        P1[b * HID + t] = p1;
        P2[b * HID + t] = p2;
    }
    if (t < 2) {
        float a = en2_b[t];
        #pragma unroll 8
        for (int k = 0; k < HID; ++k) a = fmaf(h_en[k], en2_w[k * 2 + t], a);
        out_energy[b * 2 + t] = a;
    }
    if (t >= 16 && t < 25) {
        const int j = t - 16;
        float a = st2_b[j];
        #pragma unroll 8
        for (int k = 0; k < HID; ++k) a = fmaf(h_st[k], st2_w[k * 9 + j], a);
        out_stress[b * 9 + j] = a;
    }
}

// ---------------------------------------------------------------------------
// Kernel 2: edge pair table. grid=256 (gs), block=256 (gd).
// ---------------------------------------------------------------------------
__global__ void edge_table_kernel(
    const float* __restrict__ P1, const float* __restrict__ P2,
    const float* __restrict__ ed1_b,
    const float* __restrict__ ed2_w, const float* __restrict__ ed2_b,
    float4* __restrict__ T4)
{
    const int gs = blockIdx.x;
    const int t  = threadIdx.x;

    __shared__ float p1s[HID];
    __shared__ float w2s_[HID * 3];
    __shared__ float b2s[3];

    if (t < HID) p1s[t] = P1[gs * HID + t] + ed1_b[t];
    if (t >= 64 && t < 64 + HID * 3) w2s_[t - 64] = ed2_w[t - 64];
    if (t < 3) b2s[t] = ed2_b[t];
    __syncthreads();

    float o0 = b2s[0], o1 = b2s[1], o2 = b2s[2];
    const f32x4* __restrict__ p2 = reinterpret_cast<const f32x4*>(&P2[t * HID]);
    #pragma unroll 4
    for (int k4 = 0; k4 < 16; ++k4) {
        const f32x4 pv = p2[k4];
        #pragma unroll
        for (int j = 0; j < 4; ++j) {
            const int k = k4 * 4 + j;
            const float h = fmaxf(p1s[k] + pv[j], 0.f);
            o0 = fmaf(h, w2s_[k * 3 + 0], o0);
            o1 = fmaf(h, w2s_[k * 3 + 1], o1);
            o2 = fmaf(h, w2s_[k * 3 + 2], o2);
        }
    }
    T4[gs * NB + t] = make_float4(o0, o1, o2, 0.f);
}

// ---------------------------------------------------------------------------
// Per-wave-tile LOAD / COMPUTE (macros keep LDS pointers in scope and all
// array indices compile-time — no scratch, no flat ops).
// ---------------------------------------------------------------------------
#define LOAD_TILE(U_, V_, G_, TILE_) do {                                     \
    const int node_ = (TILE_) * 16 + lrow;                                    \
    const float* ep_ = node_emb + (size_t)node_ * TWOH + kg * 8;              \
    _Pragma("unroll")                                                         \
    for (int kb = 0; kb < 4; ++kb) {                                          \
        U_[kb] = *reinterpret_cast<const f32x4*>(ep_ + kb * 32);              \
        V_[kb] = *reinterpret_cast<const f32x4*>(ep_ + kb * 32 + 4);          \
    }                                                                         \
    G_ = graph_id[node_];                                                     \
} while (0)

#define COMPUTE_TILE(U_, V_, G_, TILE_) do {                                  \
    const int node_ = (TILE_) * 16 + lrow;                                    \
    f32x4 zv_[4];                                                             \
    _Pragma("unroll")                                                         \
    for (int c2 = 0; c2 < 4; ++c2)                                            \
        zv_[c2] = *reinterpret_cast<const f32x4*>(                            \
            &zc[(size_t)(G_) * HID + c2 * 16 + kg * 4]);                      \
    f32x4 acc1_[8];                                                           \
    _Pragma("unroll")                                                         \
    for (int cht = 0; cht < 8; ++cht)                                         \
        acc1_[cht] = *reinterpret_cast<const f32x4*>(&b1L[cht * 16 + kg * 4]);\
    __builtin_amdgcn_s_setprio(1);                                            \
    _Pragma("unroll")                                                         \
    for (int kb = 0; kb < 4; ++kb) {                                          \
        half8 h_;                                                             \
        h_[0] = (_Float16)U_[kb][0]; h_[1] = (_Float16)U_[kb][1];             \
        h_[2] = (_Float16)U_[kb][2]; h_[3] = (_Float16)U_[kb][3];             \
        h_[4] = (_Float16)V_[kb][0]; h_[5] = (_Float16)V_[kb][1];             \
        h_[6] = (_Float16)V_[kb][2]; h_[7] = (_Float16)V_[kb][3];             \
        const int koff_ = (((kb * 4 + kg) ^ (lrow & 7)) << 3);                \
        _Pragma("unroll")                                                     \
        for (int cht = 0; cht < 8; ++cht) {                                   \
            const half8 w_ = *reinterpret_cast<const half8*>(                 \
                &w1L[(cht * 16 + lrow) * TWOH + koff_]);                      \
            acc1_[cht] = __builtin_amdgcn_mfma_f32_16x16x32_f16(              \
                w_, h_, acc1_[cht], 0, 0, 0);                                 \
        }                                                                     \
    }                                                                         \
    __builtin_amdgcn_s_setprio(0);                                            \
    half4 vv_[8];                                                             \
    _Pragma("unroll")                                                         \
    for (int cht = 0; cht < 8; ++cht) {                                       \
        _Pragma("unroll")                                                     \
        for (int j = 0; j < 4; ++j)                                           \
            vv_[cht][j] = (_Float16)fmaxf(acc1_[cht][j], 0.f);                \
    }                                                                         \
    f32x4 acc2_[4];                                                           \
    _Pragma("unroll")                                                         \
    for (int c2 = 0; c2 < 4; ++c2)                                            \
        acc2_[c2] = *reinterpret_cast<const f32x4*>(&b2L[c2 * 16 + kg * 4])   \
                    + zv_[c2];                                                \
    __builtin_amdgcn_s_setprio(1);                                            \
    _Pragma("unroll")                                                         \
    for (int kb = 0; kb < 4; ++kb) {                                          \
        const i32x2 a0_ = __builtin_bit_cast(i32x2, vv_[2 * kb]);             \
        const i32x2 a1_ = __builtin_bit_cast(i32x2, vv_[2 * kb + 1]);         \
        const int A0x_ = __shfl(a0_.x, srcA, 64);                             \
        const int A0y_ = __shfl(a0_.y, srcA, 64);                             \
        const int A1x_ = __shfl(a1_.x, srcA, 64);                             \
        const int A1y_ = __shfl(a1_.y, srcA, 64);                             \
        const int B0x_ = __shfl(a0_.x, srcB, 64);                             \
        const int B0y_ = __shfl(a0_.y, srcB, 64);                             \
        const int B1x_ = __shfl(a1_.x, srcB, 64);                             \
        const int B1y_ = __shfl(a1_.y, srcB, 64);                             \
        i32x4 wp_;                                                            \
        wp_.x = hi ? A1x_ : A0x_;  wp_.y = hi ? A1y_ : A0y_;                  \
        wp_.z = hi ? B1x_ : B0x_;  wp_.w = hi ? B1y_ : B0y_;                  \
        const half8 nB_ = __builtin_bit_cast(half8, wp_);                     \
        const int koff_ = (((kb * 4 + kg) ^ (lrow & 7)) << 3);                \
        _Pragma("unroll")                                                     \
        for (int c2 = 0; c2 < 4; ++c2) {                                      \
            const half8 w_ = *reinterpret_cast<const half8*>(                 \
                &w2L[(c2 * 16 + lrow) * TWOH + koff_]);                       \
            acc2_[c2] = __builtin_amdgcn_mfma_f32_16x16x32_f16(               \
                w_, nB_, acc2_[c2], 0, 0, 0);                                 \
        }                                                                     \
    }                                                                         \
    __builtin_amdgcn_s_setprio(0);                                            \
    f32x4 p_ = {0.f, 0.f, 0.f, 0.f};                                          \
    _Pragma("unroll")                                                         \
    for (int c2 = 0; c2 < 4; ++c2) {                                          \
        _Pragma("unroll")                                                     \
        for (int r = 0; r < 4; ++r) {                                         \
            const float tval_ = fmaxf(acc2_[c2][r], 0.f);                     \
            const f32x4 w3v_ = *reinterpret_cast<const f32x4*>(               \
                &w3L[(c2 * 16 + kg * 4 + r) * 4]);                            \
            p_ += tval_ * w3v_;                                               \
        }                                                                     \
    }                                                                         \
    _Pragma("unroll")                                                         \
    for (int j = 0; j < 4; ++j) {                                             \
        p_[j] += __shfl_xor(p_[j], 16, 64);                                   \
        p_[j] += __shfl_xor(p_[j], 32, 64);                                   \
    }                                                                         \
    if (kg == 0) {                                                            \
        const f32x4 b3_ = *reinterpret_cast<const f32x4*>(&nd2_b[0]);         \
        *reinterpret_cast<f32x4*>(&out_node[(size_t)node_ * 4]) = p_ + b3_;   \
    }                                                                         \
} while (0)

// ---------------------------------------------------------------------------
// Kernel 3: node path with register double-buffered tile pipeline + fused
// grid-strided edge tail. 512 blocks x 512 thr (2 blocks/CU, 1 generation).
// Each wave owns 3-4 16-node tiles; LOAD(next) issued before COMPUTE(cur)
// so ~8KB/wave stays in flight (MLP -> BW-bound, not latency-bound).
// ---------------------------------------------------------------------------
__global__ __launch_bounds__(512, 4)
void node_edge_kernel(
    const float* __restrict__ node_emb,
    const int*   __restrict__ graph_id,
    const _Float16* __restrict__ w1s,
    const float* __restrict__ nep_b,
    const _Float16* __restrict__ w2s,
    const float* __restrict__ nd1_b,
    const float* __restrict__ nd2_w, const float* __restrict__ nd2_b,
    const float* __restrict__ zc,
    const int* __restrict__ src, const int* __restrict__ dst,
    const float4* __restrict__ T4,
    float* __restrict__ out_node, float* __restrict__ out_edge)
{
    const int tid = threadIdx.x;
    const int bid = blockIdx.x;

    __shared__ _Float16 w1L[TWOH * TWOH];  // 32 KB
    __shared__ _Float16 w2L[HID * TWOH];   // 16 KB
    __shared__ float    b1L[TWOH];
    __shared__ float    b2L[HID];
    __shared__ float    w3L[HID * 4];

    // ---- stage weights into LDS (the only barrier) ----
    {
        const uint4* g1 = reinterpret_cast<const uint4*>(w1s);
        uint4* l1 = reinterpret_cast<uint4*>(w1L);
        #pragma unroll
        for (int i = 0; i < 4; ++i) l1[tid + 512 * i] = g1[tid + 512 * i];
        const uint4* g2 = reinterpret_cast<const uint4*>(w2s);
        uint4* l2 = reinterpret_cast<uint4*>(w2L);
        #pragma unroll
        for (int i = 0; i < 2; ++i) l2[tid + 512 * i] = g2[tid + 512 * i];
        if (tid < TWOH)    b1L[tid] = nep_b[tid];
        if (tid < HID)     b2L[tid] = nd1_b[tid];
        if (tid < HID * 4) w3L[tid] = nd2_w[tid];
    }
    __syncthreads();

    const int wv   = tid >> 6;
    const int lane = tid & 63;
    const int lrow = lane & 15;     // node within tile / ch row within tile
    const int kg   = lane >> 4;     // k-group
    const int hi   = kg >> 1;
    const int srcA = lrow | ((kg & 1) << 5);
    const int srcB = srcA | 16;

    // ---- node tiles: wg owns t0, t0+4096, t0+8192, (t0+12288) ----
    {
        const int wg = bid * 8 + wv;          // 0..4095
        const int t0 = wg, t1 = wg + WGS, t2 = wg + 2 * WGS, t3 = wg + 3 * WGS;
        f32x4 Ua[4], Va[4]; int Ga;
        f32x4 Ub[4], Vb[4]; int Gb;

        LOAD_TILE(Ua, Va, Ga, t0);
        LOAD_TILE(Ub, Vb, Gb, t1);            // t1 <= 8191 < WTILES always
        COMPUTE_TILE(Ua, Va, Ga, t0);
        LOAD_TILE(Ua, Va, Ga, t2);            // t2 <= 12287 < WTILES always
        COMPUTE_TILE(Ub, Vb, Gb, t1);
        const bool has3 = (t3 < WTILES);      // wg < 212
        if (has3) {
            LOAD_TILE(Ub, Vb, Gb, t3);
        }
        COMPUTE_TILE(Ua, Va, Ga, t2);
        if (has3) {
            COMPUTE_TILE(Ub, Vb, Gb, t3);
        }
    }

    // ---- edge tail: grid-strided 4-edge chunks ----
    for (int e0 = (bid * 512 + tid) * 4; e0 < NE; e0 += NODE_BLK * 512 * 4) {
        const int4 s4 = *reinterpret_cast<const int4*>(&src[e0]);
        const int4 d4 = *reinterpret_cast<const int4*>(&dst[e0]);
        const int ss[4] = {s4.x, s4.y, s4.z, s4.w};
        const int dd[4] = {d4.x, d4.y, d4.z, d4.w};
        float o[12];
        #pragma unroll
        for (int j = 0; j < 4; ++j) {
            const int gs = graph_id[ss[j]];
            const int gd = graph_id[dd[j]];
            const float4 tv = T4[gs * NB + gd];
            o[j * 3 + 0] = tv.x; o[j * 3 + 1] = tv.y; o[j * 3 + 2] = tv.z;
        }
        float4* outp = reinterpret_cast<float4*>(&out_edge[(size_t)e0 * 3]);
        outp[0] = make_float4(o[0], o[1], o[2],  o[3]);
        outp[1] = make_float4(o[4], o[5], o[6],  o[7]);
        outp[2] = make_float4(o[8], o[9], o[10], o[11]);
    }
}

// ---------------------------------------------------------------------------
extern "C" void kernel_launch(void* const* d_in, const int* in_sizes, int n_in,
                              void* d_out, int out_size, void* d_ws, size_t ws_size,
                              hipStream_t stream)
{
    const float* z        = (const float*)d_in[0];
    const float* node_emb = (const float*)d_in[1];
    const int*   graph_id = (const int*)  d_in[2];
    const int*   src      = (const int*)  d_in[3];
    const int*   dst      = (const int*)  d_in[4];
    const float* lp_w  = (const float*)d_in[5];
    const float* lp_b  = (const float*)d_in[6];
    const float* nep_w = (const float*)d_in[7];
    const float* nep_b = (const float*)d_in[8];
    const float* nd1_w = (const float*)d_in[9];
    const float* nd1_b = (const float*)d_in[10];
    const float* nd2_w = (const float*)d_in[11];
    const float* nd2_b = (const float*)d_in[12];
    const float* ed1_w = (const float*)d_in[13];
    const float* ed1_b = (const float*)d_in[14];
    const float* ed2_w = (const float*)d_in[15];
    const float* ed2_b = (const float*)d_in[16];
    const float* en1_w = (const float*)d_in[17];
    const float* en1_b = (const float*)d_in[18];
    const float* en2_w = (const float*)d_in[19];
    const float* en2_b = (const float*)d_in[20];
    const float* st1_w = (const float*)d_in[21];
    const float* st1_b = (const float*)d_in[22];
    const float* st2_w = (const float*)d_in[23];
    const float* st2_b = (const float*)d_in[24];

    float* out = (float*)d_out;
    float* out_node   = out + OUT_NODE_OFF;
    float* out_edge   = out + OUT_EDGE_OFF;
    float* out_energy = out + OUT_ENERGY_OFF;
    float* out_stress = out + OUT_STRESS_OFF;

    float* ws     = (float*)d_ws;
    float* z_proj = ws + WS_ZPROJ;
    float* zc     = ws + WS_ZC;
    float* P1     = ws + WS_P1;
    float* P2     = ws + WS_P2;
    float4* T4    = (float4*)(ws + WS_T4);
    _Float16* w1s = (_Float16*)(ws + WS_W1T);
    _Float16* w2s = (_Float16*)(ws + WS_W2T);

    precompute_kernel<<<NB + 64, 256, 0, stream>>>(
        z, lp_w, lp_b, nd1_w, ed1_w,
        en1_w, en1_b, en2_w, en2_b, st1_w, st1_b, st2_w, st2_b, nep_w,
        z_proj, zc, P1, P2, w1s, w2s, out_energy, out_stress);

    edge_table_kernel<<<NB, NB, 0, stream>>>(P1, P2, ed1_b, ed2_w, ed2_b, T4);

    node_edge_kernel<<<NODE_BLK, 512, 0, stream>>>(
        node_emb, graph_id, w1s, nep_b, w2s, nd1_b, nd2_w, nd2_b, zc,
        src, dst, T4, out_node, out_edge);
}